// Round 2
// baseline (1221.802 us; speedup 1.0000x reference)
//
#include <hip/hip_runtime.h>

// Problem constants
#define CIN   256
#define COUT  384
#define HH    56
#define WW    56
#define HO    54
#define NB    16
#define NPIX  (NB*HO*HO)   // 46656
#define KK    (CIN*9)      // 2304
#define XCH   (HH*WW)      // 3136
#define XIMG  (CIN*HH*WW)  // 802816

// GEMM tiling
#define BM 128
#define BN 128
#define BK 8

// ws layout: Wt[KK][COUT] fp32 at 0 (3,538,944 B); y[COUT][NPIX] fp32 at 4 MiB (71,663,616 B)
#define WS_Y_OFF (4u << 20)

__global__ __launch_bounds__(256) void wtrans(const float* __restrict__ w,
                                              float* __restrict__ wt) {
    int idx = blockIdx.x * 256 + threadIdx.x;   // KK*COUT = 884736 total
    int k = idx / COUT, c = idx - k * COUT;
    wt[idx] = w[c * KK + k];
}

__global__ __launch_bounds__(256) void conv_gemm(const float* __restrict__ x,
                                                 const float* __restrict__ wt,
                                                 float* __restrict__ y) {
    __shared__ float As[BK][BM];
    __shared__ float Bs[BK][BN];

    const int tid = threadIdx.x;
    const int c0 = blockIdx.y * BM;
    const int p0 = blockIdx.x * BN;

    // staging mapping: 8 k-rows x 32 groups of 4 elements
    const int ldk = tid >> 5;          // 0..7
    const int ldc = (tid & 31) << 2;   // 0..124 step 4

    // precompute the 4 pixel base offsets for B staging (clamped if OOB)
    int pb[4];
#pragma unroll
    for (int j = 0; j < 4; ++j) {
        int p = p0 + ldc + j;
        if (p >= NPIX) p = NPIX - 1;
        int b   = p / 2916;
        int rem = p - b * 2916;
        int oy  = rem / 54;
        int ox  = rem - oy * 54;
        pb[j] = b * XIMG + oy * WW + ox;
    }

    float acc[8][8];
#pragma unroll
    for (int i = 0; i < 8; ++i)
#pragma unroll
        for (int j = 0; j < 8; ++j) acc[i][j] = 0.f;

    float4 aReg;
    float  bReg0, bReg1, bReg2, bReg3;

    // prefetch it=0
    {
        int k = ldk;
        aReg = *(const float4*)(wt + k * COUT + c0 + ldc);
        int cin = k / 9, r = k - cin * 9;
        int dy = r / 3, dx = r - dy * 3;
        int off = cin * XCH + dy * WW + dx;
        bReg0 = x[pb[0] + off];
        bReg1 = x[pb[1] + off];
        bReg2 = x[pb[2] + off];
        bReg3 = x[pb[3] + off];
    }

    const int tc = (tid & 15) << 3;   // cout sub-offset 0..120
    const int tp = (tid >> 4) << 3;   // pixel sub-offset 0..120

    const int NIT = KK / BK;          // 288
    for (int it = 0; it < NIT; ++it) {
        __syncthreads();
        *(float4*)&As[ldk][ldc] = aReg;
        Bs[ldk][ldc + 0] = bReg0;
        Bs[ldk][ldc + 1] = bReg1;
        Bs[ldk][ldc + 2] = bReg2;
        Bs[ldk][ldc + 3] = bReg3;
        __syncthreads();

        if (it + 1 < NIT) {           // prefetch next chunk: overlaps with FMA below
            int k = (it + 1) * BK + ldk;
            aReg = *(const float4*)(wt + k * COUT + c0 + ldc);
            int cin = k / 9, r = k - cin * 9;
            int dy = r / 3, dx = r - dy * 3;
            int off = cin * XCH + dy * WW + dx;
            bReg0 = x[pb[0] + off];
            bReg1 = x[pb[1] + off];
            bReg2 = x[pb[2] + off];
            bReg3 = x[pb[3] + off];
        }

#pragma unroll
        for (int k = 0; k < BK; ++k) {
            float a[8], b[8];
            *(float4*)&a[0] = *(const float4*)&As[k][tc];
            *(float4*)&a[4] = *(const float4*)&As[k][tc + 4];
            *(float4*)&b[0] = *(const float4*)&Bs[k][tp];
            *(float4*)&b[4] = *(const float4*)&Bs[k][tp + 4];
#pragma unroll
            for (int i = 0; i < 8; ++i)
#pragma unroll
                for (int j = 0; j < 8; ++j)
                    acc[i][j] += a[i] * b[j];
        }
    }

    // epilogue: y[cout][pixel]; predicate whole thread (tail tile is 64 px, mult of 8)
    if (p0 + tp < NPIX) {
#pragma unroll
        for (int i = 0; i < 8; ++i) {
            float* dst = y + (c0 + tc + i) * NPIX + p0 + tp;
            *(float4*)dst       = make_float4(acc[i][0], acc[i][1], acc[i][2], acc[i][3]);
            *(float4*)(dst + 4) = make_float4(acc[i][4], acc[i][5], acc[i][6], acc[i][7]);
        }
    }
}

__global__ __launch_bounds__(256) void gate(const float* __restrict__ y,
                                            float* __restrict__ out) {
    __shared__ float ys[COUT][33];    // padded pitch: conflict-free column access
    __shared__ float gtab[COUT];
    __shared__ float pmax[8][32];
    __shared__ float mx[32];
    __shared__ int   wcnt[32];
    __shared__ int   wlist[32][4];

    const int tid = threadIdx.x;
    const int tx = tid & 31, ty = tid >> 5;   // ty 0..7
    const int p0 = blockIdx.x * 32;

    // Gaussian kernel table: kern[k] = exp(-(k-191)^2 / (2*191^2))
    for (int k = tid; k < COUT; k += 256) {
        float d = (float)(k - 191);
        gtab[k] = expf(-d * d * (1.0f / (2.0f * 191.0f * 191.0f)));
    }
    if (ty == 0) wcnt[tx] = 0;

    // stage y tile: 384 channels x 32 pixels (coalesced 128B rows)
    for (int c = ty; c < COUT; c += 8)
        ys[c][tx] = y[c * NPIX + p0 + tx];
    __syncthreads();

    // per-pixel max: 8-way partial then combine
    float m = -3.402823466e+38f;
    for (int c = ty; c < COUT; c += 8) m = fmaxf(m, ys[c][tx]);
    pmax[ty][tx] = m;
    __syncthreads();
    if (ty == 0) {
        float mm = pmax[0][tx];
#pragma unroll
        for (int r = 1; r < 8; ++r) mm = fmaxf(mm, pmax[r][tx]);
        mx[tx] = mm;
    }
    __syncthreads();

    // winner list (ties included; >4 exact ties is impossible in practice)
    const float mm = mx[tx];
    for (int c = ty; c < COUT; c += 8) {
        if (ys[c][tx] >= mm) {
            int pos = atomicAdd(&wcnt[tx], 1);
            if (pos < 4) wlist[tx][pos] = c;
        }
    }
    __syncthreads();

    // gated output, NCHW
    const int p   = p0 + tx;
    const int b   = p / 2916;
    const int rem = p - b * 2916;
    const int obase = b * (COUT * 2916) + rem;
    const int L = min(wcnt[tx], 4);
    for (int c = ty; c < COUT; c += 8) {
        float lfb = 0.f;
        for (int i = 0; i < L; ++i) {
            int d = wlist[tx][i] - c + 191;
            if (d >= 0 && d < COUT) lfb += gtab[d];
        }
        lfb = fminf(lfb, 1.0f);
        out[obase + c * 2916] = lfb * ys[c][tx];
    }
}

extern "C" void kernel_launch(void* const* d_in, const int* in_sizes, int n_in,
                              void* d_out, int out_size, void* d_ws, size_t ws_size,
                              hipStream_t stream) {
    const float* x = (const float*)d_in[0];
    const float* w = (const float*)d_in[1];
    float* outp = (float*)d_out;

    float* wt = (float*)d_ws;                              // 3.46 MB
    float* y  = (float*)((char*)d_ws + WS_Y_OFF);          // 71.7 MB
    // total ws need ~75.9 MB

    wtrans<<<(KK * COUT) / 256, 256, 0, stream>>>(w, wt);

    dim3 grid((NPIX + BN - 1) / BN, COUT / BM);            // (365, 3)
    conv_gemm<<<grid, 256, 0, stream>>>(x, wt, y);

    gate<<<NPIX / 32, 256, 0, stream>>>(y, outp);
}